// Round 1
// baseline (534.136 us; speedup 1.0000x reference)
//
#include <hip/hip_runtime.h>
#include <math.h>

#define TILE_H 16
#define NPI 8
#define NTOK 9
#define DIM 128
#define DFF 512
#define TTW 64

__global__ __launch_bounds__(256, 2)
void dg3_fused(const float* __restrict__ hf,
               const float* __restrict__ w_q,
               const float* __restrict__ W1,
               const float* __restrict__ b1,
               const float* __restrict__ gamma,
               const float* __restrict__ beta,
               const float* __restrict__ W2,
               const float* __restrict__ b2,
               const int* __restrict__ pi,
               const int* __restrict__ stats,
               const int* __restrict__ po,
               float* __restrict__ out,
               int H)
{
    __shared__ float A[TILE_H][DIM + 4];    // +4 pad: 528B row, 16B-aligned
    __shared__ float Hs[TILE_H][DFF + 4];   // +4 pad: 2064B row, 16B-aligned

    const int t = threadIdx.x;
    const int tile = blockIdx.x;
    const int hop0 = tile * TILE_H;

    // ---- Phase 1: gather + masked attention pooling (32 lanes per hop) ----
    {
        const int l = t & 31;          // lane within half-wave; owns dims l*4..l*4+3
        const int g = t >> 5;          // 0..7 half-wave group id
        const float4 wq4 = *(const float4*)(w_q + l * 4);
        #pragma unroll
        for (int it = 0; it < 2; ++it) {
            const int hl = g + it * 8;
            const int hop = hop0 + hl;
            if (hop < H) {
                float4 tok[NTOK];
                float sc[NTOK];
                bool val[NTOK];
                #pragma unroll
                for (int p = 0; p < NPI; ++p) {
                    int idx = pi[hop * NPI + p];
                    val[p] = (stats[hop * NPI + p] != -1);
                    tok[p] = *(const float4*)(hf + (size_t)idx * DIM + l * 4);
                }
                {
                    int idx8 = po[hop];
                    val[8] = true;
                    tok[8] = *(const float4*)(hf + (size_t)idx8 * DIM + l * 4);
                }
                #pragma unroll
                for (int p = 0; p < NTOK; ++p) {
                    sc[p] = tok[p].x * wq4.x + tok[p].y * wq4.y
                          + tok[p].z * wq4.z + tok[p].w * wq4.w;
                }
                // reduce partial dots across the 32 lanes (masks < 32 stay in half-wave)
                #pragma unroll
                for (int m = 1; m < 32; m <<= 1) {
                    #pragma unroll
                    for (int p = 0; p < NTOK; ++p)
                        sc[p] += __shfl_xor(sc[p], m);
                }
                const float isd = 0.08838834764831845f;  // 1/sqrt(128)
                float mx = -1e30f;
                #pragma unroll
                for (int p = 0; p < NTOK; ++p) {
                    sc[p] = val[p] ? sc[p] * isd : -1e30f;
                    mx = fmaxf(mx, sc[p]);
                }
                float se = 0.f;
                #pragma unroll
                for (int p = 0; p < NTOK; ++p) { sc[p] = expf(sc[p] - mx); se += sc[p]; }
                const float inv = 1.f / se;
                float4 acc = {0.f, 0.f, 0.f, 0.f};
                #pragma unroll
                for (int p = 0; p < NTOK; ++p) {
                    float a = sc[p] * inv;
                    acc.x += a * tok[p].x; acc.y += a * tok[p].y;
                    acc.z += a * tok[p].z; acc.w += a * tok[p].w;
                }
                *(float4*)&A[hl][l * 4] = acc;
            } else {
                float4 z = {0.f, 0.f, 0.f, 0.f};
                *(float4*)&A[hl][l * 4] = z;
            }
        }
    }
    __syncthreads();

    // ---- Phase 2: Hs = relu(A @ W1 + b1)  (thread t owns columns t, t+256) ----
    {
        const int j0 = t, j1 = t + 256;
        float acc0[TILE_H], acc1[TILE_H];
        #pragma unroll
        for (int i = 0; i < TILE_H; ++i) { acc0[i] = 0.f; acc1[i] = 0.f; }
        for (int d = 0; d < DIM; d += 4) {
            // coalesced: consecutive t -> consecutive W1 addresses (L2-resident)
            float w00 = W1[(d + 0) * DFF + j0], w10 = W1[(d + 0) * DFF + j1];
            float w01 = W1[(d + 1) * DFF + j0], w11 = W1[(d + 1) * DFF + j1];
            float w02 = W1[(d + 2) * DFF + j0], w12 = W1[(d + 2) * DFF + j1];
            float w03 = W1[(d + 3) * DFF + j0], w13 = W1[(d + 3) * DFF + j1];
            #pragma unroll
            for (int i = 0; i < TILE_H; ++i) {
                float4 a = *(const float4*)&A[i][d];  // LDS broadcast (same addr all lanes)
                acc0[i] += a.x * w00 + a.y * w01 + a.z * w02 + a.w * w03;
                acc1[i] += a.x * w10 + a.y * w11 + a.z * w12 + a.w * w13;
            }
        }
        float bb0 = b1[j0], bb1 = b1[j1];
        #pragma unroll
        for (int i = 0; i < TILE_H; ++i) {
            Hs[i][j0] = fmaxf(acc0[i] + bb0, 0.f);
            Hs[i][j1] = fmaxf(acc1[i] + bb1, 0.f);
        }
    }
    __syncthreads();

    // ---- Phase 3: LayerNorm per hop over DFF (16 lanes per hop) ----
    {
        const int hl = t >> 4;     // 0..15
        const int s = t & 15;
        float sum = 0.f, ssq = 0.f;
        #pragma unroll
        for (int k = 0; k < DFF / 16; ++k) {
            float v = Hs[hl][s + 16 * k];
            sum += v; ssq += v * v;
        }
        #pragma unroll
        for (int m = 1; m < 16; m <<= 1) {
            sum += __shfl_xor(sum, m);
            ssq += __shfl_xor(ssq, m);
        }
        const float invn = 1.f / (float)DFF;
        float mu = sum * invn;
        float var = ssq * invn - mu * mu;
        float rs = rsqrtf(var + 1e-5f);
        #pragma unroll
        for (int k = 0; k < DFF / 16; ++k) {
            int j = s + 16 * k;
            float v = Hs[hl][j];
            Hs[hl][j] = (v - mu) * rs * gamma[j] + beta[j];
        }
    }
    __syncthreads();

    // ---- Phase 4: out = Hs @ W2 + b2  (wave owns 4 hops x 64 logits) ----
    {
        const int tt = t & 63;
        const int hg = t >> 6;   // 0..3
        float acc[4] = {0.f, 0.f, 0.f, 0.f};
        for (int k = 0; k < DFF; k += 4) {
            // coalesced: 64 lanes read 256B contiguous rows of W2 (L2-resident)
            float w0 = W2[(k + 0) * TTW + tt];
            float w1 = W2[(k + 1) * TTW + tt];
            float w2 = W2[(k + 2) * TTW + tt];
            float w3 = W2[(k + 3) * TTW + tt];
            #pragma unroll
            for (int i = 0; i < 4; ++i) {
                float4 h4 = *(const float4*)&Hs[hg * 4 + i][k];  // broadcast in wave
                acc[i] += h4.x * w0 + h4.y * w1 + h4.z * w2 + h4.w * w3;
            }
        }
        float bb = b2[tt];
        #pragma unroll
        for (int i = 0; i < 4; ++i) {
            int hop = hop0 + hg * 4 + i;
            if (hop < H)
                out[(size_t)hop * TTW + tt] = acc[i] + bb;
        }
    }
}

extern "C" void kernel_launch(void* const* d_in, const int* in_sizes, int n_in,
                              void* d_out, int out_size, void* d_ws, size_t ws_size,
                              hipStream_t stream) {
    const float* hf    = (const float*)d_in[0];
    const float* w_q   = (const float*)d_in[1];
    const float* W1    = (const float*)d_in[2];
    const float* b1    = (const float*)d_in[3];
    const float* gamma = (const float*)d_in[4];
    const float* beta  = (const float*)d_in[5];
    const float* W2    = (const float*)d_in[6];
    const float* b2    = (const float*)d_in[7];
    const int* pi      = (const int*)d_in[8];
    const int* stats   = (const int*)d_in[9];
    const int* po      = (const int*)d_in[10];
    float* out         = (float*)d_out;

    const int H = in_sizes[10];                 // all_hop_po element count
    const int n_tiles = (H + TILE_H - 1) / TILE_H;

    hipLaunchKernelGGL(dg3_fused, dim3(n_tiles), dim3(256), 0, stream,
                       hf, w_q, W1, b1, gamma, beta, W2, b2,
                       pi, stats, po, out, H);
}

// Round 2
// 224.954 us; speedup vs baseline: 2.3744x; 2.3744x over previous
//
#include <hip/hip_runtime.h>
#include <math.h>

#define TILE_H 32
#define NPI 8
#define NTOK 9
#define DIM 128
#define DFF 512
#define TTW 64

typedef __attribute__((ext_vector_type(8))) short short8;
typedef __attribute__((ext_vector_type(4))) float float4v;

__device__ __forceinline__ unsigned short f32_bf16(float f) {
    union { float f; unsigned u; } v; v.f = f;
    unsigned r = v.u + 0x7FFFu + ((v.u >> 16) & 1u);   // RNE
    return (unsigned short)(r >> 16);
}
__device__ __forceinline__ float bf16_f32(unsigned short h) {
    union { unsigned u; float f; } v; v.u = (unsigned)h << 16;
    return v.f;
}

// ---- prep: W1[128][512] -> W1T bf16 [512][128]; W2[512][64] -> W2T bf16 [64][512]
__global__ void prep_weights(const float* __restrict__ W1,
                             const float* __restrict__ W2,
                             unsigned short* __restrict__ w1t,
                             unsigned short* __restrict__ w2t) {
    int id = blockIdx.x * 256 + threadIdx.x;
    if (id < DIM * DFF) {
        int k = id >> 9, n = id & 511;           // W1 row-major [k][n]
        w1t[n * DIM + k] = f32_bf16(W1[id]);
    } else {
        int j = id - DIM * DFF;
        if (j < DFF * TTW) {
            int k = j >> 6, n = j & 63;          // W2 row-major [k][n]
            w2t[n * DFF + k] = f32_bf16(W2[j]);
        }
    }
}

__global__ __launch_bounds__(256, 2)
void dg3_fused(const float* __restrict__ hf,
               const float* __restrict__ w_q,
               const unsigned short* __restrict__ w1t,   // bf16 [512][128]
               const float* __restrict__ b1,
               const float* __restrict__ gamma,
               const float* __restrict__ beta,
               const unsigned short* __restrict__ w2t,   // bf16 [64][512]
               const float* __restrict__ b2,
               const int* __restrict__ pi,
               const int* __restrict__ stats,
               const int* __restrict__ po,
               float* __restrict__ out,
               int H)
{
    // Apool row stride 136 bf16 = 272 B -> bank stride 4 words: 2-way on b128 (free)
    __shared__ unsigned short Apool[TILE_H][DIM + 8];
    // Hs row stride 520 bf16 = 1040 B -> bank stride 4 words: 2-way on b128 (free)
    __shared__ unsigned short Hsm[TILE_H][DFF + 8];

    const int t    = threadIdx.x;
    const int lane = t & 63;
    const int w    = t >> 6;          // wave 0..3
    const int row  = lane & 15;
    const int quad = lane >> 4;
    const int hop0 = blockIdx.x * TILE_H;

    // ================= Phase 1: gather + masked attention pooling =================
    {
        const int l = t & 31;                 // half-wave lane; owns dims 4l..4l+3
        const int g = t >> 5;                 // 0..7
        const float4v wq4 = *(const float4v*)(w_q + l * 4);
        #pragma unroll
        for (int it = 0; it < 4; ++it) {
            const int hl = g + it * 8;
            const int hop = hop0 + hl;
            unsigned long long packed = 0;
            if (hop < H) {
                float4v tok[NTOK];
                float sc[NTOK];
                bool val[NTOK];
                #pragma unroll
                for (int p = 0; p < NPI; ++p) {
                    int idx = pi[hop * NPI + p];
                    val[p] = (stats[hop * NPI + p] != -1);
                    tok[p] = *(const float4v*)(hf + (size_t)idx * DIM + l * 4);
                }
                {
                    int idx8 = po[hop];
                    val[8] = true;
                    tok[8] = *(const float4v*)(hf + (size_t)idx8 * DIM + l * 4);
                }
                #pragma unroll
                for (int p = 0; p < NTOK; ++p)
                    sc[p] = tok[p][0]*wq4[0] + tok[p][1]*wq4[1]
                          + tok[p][2]*wq4[2] + tok[p][3]*wq4[3];
                #pragma unroll
                for (int m = 1; m < 32; m <<= 1) {
                    #pragma unroll
                    for (int p = 0; p < NTOK; ++p) sc[p] += __shfl_xor(sc[p], m);
                }
                const float isd = 0.08838834764831845f;   // 1/sqrt(128)
                float mx = -1e30f;
                #pragma unroll
                for (int p = 0; p < NTOK; ++p) {
                    sc[p] = val[p] ? sc[p] * isd : -1e30f;
                    mx = fmaxf(mx, sc[p]);
                }
                float se = 0.f;
                #pragma unroll
                for (int p = 0; p < NTOK; ++p) { sc[p] = __expf(sc[p] - mx); se += sc[p]; }
                const float inv = 1.f / se;
                float a0=0.f, a1=0.f, a2=0.f, a3=0.f;
                #pragma unroll
                for (int p = 0; p < NTOK; ++p) {
                    float a = sc[p] * inv;
                    a0 += a * tok[p][0]; a1 += a * tok[p][1];
                    a2 += a * tok[p][2]; a3 += a * tok[p][3];
                }
                packed =  (unsigned long long)f32_bf16(a0)
                       | ((unsigned long long)f32_bf16(a1) << 16)
                       | ((unsigned long long)f32_bf16(a2) << 32)
                       | ((unsigned long long)f32_bf16(a3) << 48);
            }
            *(unsigned long long*)&Apool[hl][l * 4] = packed;
        }
    }
    __syncthreads();

    // ========== Phase 2: GEMM1 (swapped: A=W1T [n][k], B=pooled^T [k][hop]) ==========
    // wave w owns out-dims [w*128, w*128+128): 8 Mtiles x 2 hop-Ntiles x 4 Ksteps
    {
        float4v acc1[8][2];
        #pragma unroll
        for (int mt = 0; mt < 8; ++mt)
            #pragma unroll
            for (int ht = 0; ht < 2; ++ht)
                acc1[mt][ht] = (float4v){0.f, 0.f, 0.f, 0.f};

        #pragma unroll
        for (int ks = 0; ks < 4; ++ks) {
            const int k0 = ks * 32 + quad * 8;
            short8 bfr[2];
            #pragma unroll
            for (int ht = 0; ht < 2; ++ht)
                bfr[ht] = *(const short8*)&Apool[ht * 16 + row][k0];
            #pragma unroll
            for (int mt = 0; mt < 8; ++mt) {
                short8 afr = *(const short8*)(w1t + (size_t)(w * 128 + mt * 16 + row) * DIM + k0);
                #pragma unroll
                for (int ht = 0; ht < 2; ++ht)
                    acc1[mt][ht] = __builtin_amdgcn_mfma_f32_16x16x32_bf16(
                        afr, bfr[ht], acc1[mt][ht], 0, 0, 0);
            }
        }
        // epilogue: bias + ReLU + bf16 pack -> Hs[hop][n]; 4 consecutive n per reg group
        #pragma unroll
        for (int mt = 0; mt < 8; ++mt) {
            const int nb = w * 128 + mt * 16 + quad * 4;
            const float4v bias = *(const float4v*)(b1 + nb);
            #pragma unroll
            for (int ht = 0; ht < 2; ++ht) {
                unsigned long long p = 0;
                #pragma unroll
                for (int r = 0; r < 4; ++r) {
                    float v = fmaxf(acc1[mt][ht][r] + bias[r], 0.f);
                    p |= (unsigned long long)f32_bf16(v) << (16 * r);
                }
                *(unsigned long long*)&Hsm[ht * 16 + row][nb] = p;
            }
        }
    }
    __syncthreads();

    // ================= Phase 3: LayerNorm (8 lanes per row, in place) =================
    {
        const int r = t >> 3;            // 0..31
        const int s = t & 7;
        float sum = 0.f, ssq = 0.f;
        #pragma unroll
        for (int k = 0; k < 8; ++k) {
            short8 hv = *(const short8*)&Hsm[r][s * 8 + k * 64];
            #pragma unroll
            for (int e = 0; e < 8; ++e) {
                float v = bf16_f32((unsigned short)hv[e]);
                sum += v; ssq += v * v;
            }
        }
        #pragma unroll
        for (int m = 1; m < 8; m <<= 1) {
            sum += __shfl_xor(sum, m);
            ssq += __shfl_xor(ssq, m);
        }
        const float invn = 1.f / (float)DFF;
        float mu  = sum * invn;
        float var = ssq * invn - mu * mu;
        float rs  = rsqrtf(var + 1e-5f);
        #pragma unroll
        for (int k = 0; k < 8; ++k) {
            const int col = s * 8 + k * 64;
            short8 hv = *(const short8*)&Hsm[r][col];
            float4v g0 = *(const float4v*)(gamma + col);
            float4v g1 = *(const float4v*)(gamma + col + 4);
            float4v be0 = *(const float4v*)(beta + col);
            float4v be1 = *(const float4v*)(beta + col + 4);
            unsigned long long p0 = 0, p1 = 0;
            #pragma unroll
            for (int e = 0; e < 4; ++e) {
                float tg = rs * g0[e];
                float o  = bf16_f32((unsigned short)hv[e]) * tg + (be0[e] - mu * tg);
                p0 |= (unsigned long long)f32_bf16(o) << (16 * e);
            }
            #pragma unroll
            for (int e = 0; e < 4; ++e) {
                float tg = rs * g1[e];
                float o  = bf16_f32((unsigned short)hv[4 + e]) * tg + (be1[e] - mu * tg);
                p1 |= (unsigned long long)f32_bf16(o) << (16 * e);
            }
            *(unsigned long long*)&Hsm[r][col]     = p0;
            *(unsigned long long*)&Hsm[r][col + 4] = p1;
        }
    }
    __syncthreads();

    // ========== Phase 4: GEMM2 (A=Hs [hop][k], B=W2T-asB [k][tt]); wave w: tt tile w ==========
    {
        float4v acc2[2];
        acc2[0] = (float4v){0.f,0.f,0.f,0.f};
        acc2[1] = (float4v){0.f,0.f,0.f,0.f};
        #pragma unroll
        for (int ks = 0; ks < 16; ++ks) {
            const int k0 = ks * 32 + quad * 8;
            short8 bfr = *(const short8*)(w2t + (size_t)(w * 16 + row) * DFF + k0);
            #pragma unroll
            for (int mt = 0; mt < 2; ++mt) {
                short8 afr = *(const short8*)&Hsm[mt * 16 + row][k0];
                acc2[mt] = __builtin_amdgcn_mfma_f32_16x16x32_bf16(
                    afr, bfr, acc2[mt], 0, 0, 0);
            }
        }
        const float bb = b2[w * 16 + row];
        #pragma unroll
        for (int mt = 0; mt < 2; ++mt) {
            #pragma unroll
            for (int r = 0; r < 4; ++r) {
                int hop = hop0 + mt * 16 + quad * 4 + r;
                if (hop < H)
                    out[(size_t)hop * TTW + w * 16 + row] = acc2[mt][r] + bb;
            }
        }
    }
}

extern "C" void kernel_launch(void* const* d_in, const int* in_sizes, int n_in,
                              void* d_out, int out_size, void* d_ws, size_t ws_size,
                              hipStream_t stream) {
    const float* hf    = (const float*)d_in[0];
    const float* w_q   = (const float*)d_in[1];
    const float* W1    = (const float*)d_in[2];
    const float* b1    = (const float*)d_in[3];
    const float* gamma = (const float*)d_in[4];
    const float* beta  = (const float*)d_in[5];
    const float* W2    = (const float*)d_in[6];
    const float* b2    = (const float*)d_in[7];
    const int* pi      = (const int*)d_in[8];
    const int* stats   = (const int*)d_in[9];
    const int* po      = (const int*)d_in[10];
    float* out         = (float*)d_out;

    unsigned short* w1t = (unsigned short*)d_ws;                       // 512*128 bf16
    unsigned short* w2t = (unsigned short*)((char*)d_ws + DIM*DFF*2);  // 64*512 bf16

    const int H = in_sizes[10];
    const int n_tiles = (H + TILE_H - 1) / TILE_H;
    const int prep_threads = DIM * DFF + DFF * TTW;   // 98304

    hipLaunchKernelGGL(prep_weights, dim3((prep_threads + 255) / 256), dim3(256), 0, stream,
                       W1, W2, w1t, w2t);
    hipLaunchKernelGGL(dg3_fused, dim3(n_tiles), dim3(256), 0, stream,
                       hf, w_q, w1t, b1, gamma, beta, w2t, b2,
                       pi, stats, po, out, H);
}